// Round 9
// baseline (78.545 us; speedup 1.0000x reference)
//
#include <hip/hip_runtime.h>

#define NPIX 16384
#define WIDTH 128
#define JC 64            // j-slices
#define JLEN (NPIX / JC) // 256 B-points per slice
#define APT 4            // A-points per thread
#define ABLK (256 * APT) // 1024 A-points per block

// depth -> (x, y, z, |p|^2 + inf_add). Same math as reference pixel2xyz.
__device__ __forceinline__ float4 make_point(float d, int p,
    float fu, float cu, float p03, float fv, float cv, float p13, float p23,
    float inf_add) {
    float px = (float)(p & (WIDTH - 1));
    float py = (float)(p >> 7);
    float x = (px * (d + p23) - (cu * d + p03)) / fu;
    float y = (py * (d + p23) - (cv * d + p13)) / fv;
    float s = x * x + y * y + d * d;
    return make_float4(x, y, d, s + inf_add);
}

// ---------------------------------------------------------------------------
// Kernel 1: depth -> point clouds. .w = |p|^2 (+1e30 if target<=0 — the
// B-side mask: masked pairs lose the min; A-side masked in reduce).
// ---------------------------------------------------------------------------
__global__ __launch_bounds__(256) void pc_precompute_kernel(
    const float* __restrict__ pred,
    const float* __restrict__ target,
    const float* __restrict__ P,
    float4* __restrict__ pcT,
    float4* __restrict__ pcP) {
    int p = blockIdx.x * blockDim.x + threadIdx.x;
    float fu = P[0], cu = P[2], p03 = P[3];
    float fv = P[5], cv = P[6], p13 = P[7], p23 = P[11];
    float dt = target[p];
    float dp = pred[p];
    float inf_add = (dt > 0.0f) ? 0.0f : 1e30f;
    pcT[p] = make_point(dt, p, fu, cu, p03, fv, cv, p13, p23, inf_add);
    pcP[p] = make_point(dp, p, fu, cu, p03, fv, cv, p13, p23, inf_add);
}

// ---------------------------------------------------------------------------
// Kernel 2: pairwise min. No LDS, no barriers. B is read with wave-uniform
// addresses *laundered through a VGPR* so the compiler emits vector
// global_load_dwordx4 (one L1-broadcast transaction/wave) instead of s_load
// (R5's SGPR-operand hazard) and the LDS pipe stays idle (R2/R6's second
// bottleneck). VMEM:VALU = 2 loads : 28 instrs per 2 B-points -> pure
// VALU-bound at 3.5 instr/pair. Invalid B carries +1e30 in w.
// ---------------------------------------------------------------------------
__global__ __launch_bounds__(256, 8) void pair_min_kernel(
    const float4* __restrict__ pcT,
    const float4* __restrict__ pcP,
    float* __restrict__ pm12,
    float* __restrict__ pm21) {
    const float4* __restrict__ A;
    const float4* __restrict__ B;
    float* __restrict__ pm;
    if (blockIdx.z == 0) { A = pcT; B = pcP; pm = pm12; }
    else                 { A = pcP; B = pcT; pm = pm21; }

    int t = threadIdx.x;
    int abase = blockIdx.x * ABLK + t;

    float ax[APT], ay[APT], az[APT], mn[APT];
    #pragma unroll
    for (int k = 0; k < APT; ++k) {
        float4 a = A[abase + k * 256];
        ax[k] = -2.0f * a.x;
        ay[k] = -2.0f * a.y;
        az[k] = -2.0f * a.z;
        mn[k] = 3e38f;
    }

    // Launder the (uniform) B-slice base index into a VGPR so downstream
    // addressing is treated as divergent -> global_load_dwordx4, not s_load.
    int jbase = blockIdx.y * JLEN;
    int jb_l;
    asm("v_mov_b32 %0, %1" : "=v"(jb_l) : "v"(jbase));
    const float4* __restrict__ Bt = B + jb_l;

    #pragma unroll 4
    for (int j = 0; j < JLEN; j += 2) {
        float4 b0 = Bt[j];     // same addr across lanes -> 1 L1 txn
        float4 b1 = Bt[j + 1];
        #pragma unroll
        for (int k = 0; k < APT; ++k) {
            float e0 = fmaf(ax[k], b0.x, fmaf(ay[k], b0.y, fmaf(az[k], b0.z, b0.w)));
            float e1 = fmaf(ax[k], b1.x, fmaf(ay[k], b1.y, fmaf(az[k], b1.z, b1.w)));
            mn[k] = fminf(fminf(e0, e1), mn[k]); // -> v_min3_f32
        }
    }

    int obase = blockIdx.y * NPIX + abase;
    #pragma unroll
    for (int k = 0; k < APT; ++k) pm[obase + k * 256] = mn[k];
}

// ---------------------------------------------------------------------------
// Kernel 3: reduce. 256 blocks; each owns 64 A-points, threads split the JC
// slices 4-way (min exactly associative), LDS-combine, |a|^2 add-back,
// masked deterministic sum.
// ---------------------------------------------------------------------------
__global__ __launch_bounds__(256) void reduce_kernel(
    const float* __restrict__ pm12,
    const float* __restrict__ pm21,
    const float4* __restrict__ pcT,
    const float4* __restrict__ pcP,
    const float* __restrict__ target,
    float* __restrict__ bsum,
    float* __restrict__ bn) {
    int t = threadIdx.x;
    int al = t & 63, q = t >> 6;
    int a = blockIdx.x * 64 + al;

    float m12 = 3e38f, m21 = 3e38f;
    int jc0 = q * (JC / 4);
    for (int jc = jc0; jc < jc0 + JC / 4; ++jc) {
        m12 = fminf(m12, pm12[jc * NPIX + a]);
        m21 = fminf(m21, pm21[jc * NPIX + a]);
    }
    __shared__ float s12[4][64], s21[4][64];
    s12[q][al] = m12;
    s21[q][al] = m21;
    __syncthreads();

    if (t < 64) {
        m12 = fminf(fminf(s12[0][t], s12[1][t]), fminf(s12[2][t], s12[3][t]));
        m21 = fminf(fminf(s21[0][t], s21[1][t]), fminf(s21[2][t], s21[3][t]));

        float v = (target[a] > 0.0f) ? 1.0f : 0.0f;
        // valid a: .w is clean |p|^2; invalid a: masked by v=0
        float contrib = v * ((m12 + pcT[a].w) + (m21 + pcP[a].w));

        for (int o = 32; o > 0; o >>= 1) {
            contrib += __shfl_down(contrib, o);
            v += __shfl_down(v, o);
        }
        if (t == 0) {
            bsum[blockIdx.x] = contrib;
            bn[blockIdx.x] = v;
        }
    }
}

// ---------------------------------------------------------------------------
// Kernel 4: fixed-order lane-parallel sum of 256 partials (deterministic).
// ---------------------------------------------------------------------------
__global__ void final_kernel(const float* __restrict__ bsum,
                             const float* __restrict__ bn,
                             float* __restrict__ out) {
    int t = threadIdx.x; // 64 threads
    float s = 0.0f, n = 0.0f;
    for (int i = t; i < 256; i += 64) { s += bsum[i]; n += bn[i]; }
    for (int o = 32; o > 0; o >>= 1) {
        s += __shfl_down(s, o);
        n += __shfl_down(n, o);
    }
    if (t == 0) out[0] = s / n;
}

extern "C" void kernel_launch(void* const* d_in, const int* in_sizes, int n_in,
                              void* d_out, int out_size, void* d_ws, size_t ws_size,
                              hipStream_t stream) {
    const float* pred   = (const float*)d_in[0];
    const float* target = (const float*)d_in[1];
    const float* P      = (const float*)d_in[2];
    float* out = (float*)d_out;

    char* ws = (char*)d_ws;
    float4* pcT = (float4*)ws;                            // NPIX float4
    float4* pcP = (float4*)(ws + (size_t)NPIX * 16);
    float* pm12 = (float*)(ws + (size_t)NPIX * 32);       // JC*NPIX floats
    float* pm21 = pm12 + (size_t)JC * NPIX;
    float* bsum = pm21 + (size_t)JC * NPIX;               // 256 + 256
    float* bn   = bsum + 256;

    pc_precompute_kernel<<<dim3(NPIX / 256), 256, 0, stream>>>(pred, target, P, pcT, pcP);

    dim3 grid(NPIX / ABLK, JC, 2); // (16, 64, 2) = 2048 blocks
    pair_min_kernel<<<grid, 256, 0, stream>>>(pcT, pcP, pm12, pm21);

    reduce_kernel<<<dim3(256), 256, 0, stream>>>(pm12, pm21, pcT, pcP, target, bsum, bn);
    final_kernel<<<1, 64, 0, stream>>>(bsum, bn, out);
}

// Round 10
// 65.665 us; speedup vs baseline: 1.1962x; 1.1962x over previous
//
#include <hip/hip_runtime.h>

#define NPIX 16384
#define WIDTH 128
#define APT 8            // A-points per thread
#define ABLK (256 * APT) // 2048 A-points per block
#define TILE 128         // B-points staged per LDS tile

// depth -> (x, y, z, |p|^2 + inf_add). Same math as reference pixel2xyz.
__device__ __forceinline__ float4 make_point(float d, int p,
    float fu, float cu, float p03, float fv, float cv, float p13, float p23,
    float inf_add) {
    float px = (float)(p & (WIDTH - 1));
    float py = (float)(p >> 7);
    float x = (px * (d + p23) - (cu * d + p03)) / fu;
    float y = (py * (d + p23) - (cv * d + p13)) / fv;
    float s = x * x + y * y + d * d;
    return make_float4(x, y, d, s + inf_add);
}

// ---------------------------------------------------------------------------
// Pairwise-min kernel (precompute fused). The proven R2 structure (LDS
// broadcast, scalar FMA, 2048 blocks) with APT=8 so the LDS pipe (1 b128
// per B-point per wave, serving 8 A-points) drops to ~20us — below the
// ~24us VALU floor of 3.5 instr/pair. jlen == TILE -> exactly one barrier
// pair per block. Invalid pixels (target<=0) carry +1e30 in b.w -> masked
// pairs lose the min; |a|^2 added back in reduce. No atomics (R4 lesson),
// no packed math (R8 lesson: pk_fma is not 2x on gfx950), no uniform global
// loads (R9 lesson).
// ---------------------------------------------------------------------------
__global__ __launch_bounds__(256, 8) void pair_min_kernel(
    const float* __restrict__ pred,
    const float* __restrict__ target,
    const float* __restrict__ P,
    float* __restrict__ pm12,
    float* __restrict__ pm21,
    int jlen) {
    float fu = P[0], cu = P[2], p03 = P[3];
    float fv = P[5], cv = P[6], p13 = P[7], p23 = P[11];

    const float* __restrict__ dA;
    const float* __restrict__ dB;
    float* __restrict__ pm;
    if (blockIdx.z == 0) { dA = target; dB = pred;   pm = pm12; }
    else                 { dA = pred;   dB = target; pm = pm21; }

    __shared__ float4 sB[TILE];
    int t = threadIdx.x;

    // A points: 8 per thread, -2 folded (|a|^2 added back in reduce).
    int abase = blockIdx.x * ABLK + t;
    float ax[APT], ay[APT], az[APT], mn[APT];
    #pragma unroll
    for (int k = 0; k < APT; ++k) {
        int a = abase + k * 256;
        float4 pa = make_point(dA[a], a, fu, cu, p03, fv, cv, p13, p23, 0.0f);
        ax[k] = -2.0f * pa.x;
        ay[k] = -2.0f * pa.y;
        az[k] = -2.0f * pa.z;
        mn[k] = 3e38f;
    }

    int jbase = blockIdx.y * jlen;
    for (int jt = 0; jt < jlen; jt += TILE) {
        __syncthreads();
        if (t < TILE) {
            int jb = jbase + jt + t;
            float tb = target[jb];
            float inf_add = (tb > 0.0f) ? 0.0f : 1e30f;
            sB[t] = make_point(dB[jb], jb, fu, cu, p03, fv, cv, p13, p23, inf_add);
        }
        __syncthreads();

        #pragma unroll 2
        for (int j = 0; j < TILE; j += 2) {
            float4 b0 = sB[j];     // broadcast ds_read_b128
            float4 b1 = sB[j + 1];
            #pragma unroll
            for (int k = 0; k < APT; ++k) {
                float e0 = fmaf(ax[k], b0.x, fmaf(ay[k], b0.y, fmaf(az[k], b0.z, b0.w)));
                float e1 = fmaf(ax[k], b1.x, fmaf(ay[k], b1.y, fmaf(az[k], b1.z, b1.w)));
                mn[k] = fminf(fminf(e0, e1), mn[k]); // -> v_min3_f32
            }
        }
    }

    int obase = blockIdx.y * NPIX + abase;
    #pragma unroll
    for (int k = 0; k < APT; ++k) pm[obase + k * 256] = mn[k];
}

// ---------------------------------------------------------------------------
// Reduce: 256 blocks; each owns 64 A-points, threads split the JC slices
// 4-way (min exactly associative), LDS-combine, |a|^2 add-back, masked
// deterministic sum. Recomputes |a|^2 from depth.
// ---------------------------------------------------------------------------
__global__ __launch_bounds__(256) void reduce_kernel(
    const float* __restrict__ pm12,
    const float* __restrict__ pm21,
    const float* __restrict__ pred,
    const float* __restrict__ target,
    const float* __restrict__ P,
    int jc,
    float* __restrict__ bsum,
    float* __restrict__ bn) {
    int t = threadIdx.x;
    int al = t & 63, q = t >> 6;
    int a = blockIdx.x * 64 + al;

    float m12 = 3e38f, m21 = 3e38f;
    int per = jc >> 2;
    int jc0 = q * per;
    for (int j = jc0; j < jc0 + per; ++j) {
        m12 = fminf(m12, pm12[j * NPIX + a]);
        m21 = fminf(m21, pm21[j * NPIX + a]);
    }
    __shared__ float s12[4][64], s21[4][64];
    s12[q][al] = m12;
    s21[q][al] = m21;
    __syncthreads();

    if (t < 64) {
        m12 = fminf(fminf(s12[0][t], s12[1][t]), fminf(s12[2][t], s12[3][t]));
        m21 = fminf(fminf(s21[0][t], s21[1][t]), fminf(s21[2][t], s21[3][t]));

        float fu = P[0], cu = P[2], p03 = P[3];
        float fv = P[5], cv = P[6], p13 = P[7], p23 = P[11];
        float dt = target[a], dp = pred[a];
        float v = (dt > 0.0f) ? 1.0f : 0.0f;
        float4 pT = make_point(dt, a, fu, cu, p03, fv, cv, p13, p23, 0.0f);
        float4 pP = make_point(dp, a, fu, cu, p03, fv, cv, p13, p23, 0.0f);
        float contrib = v * ((m12 + pT.w) + (m21 + pP.w));

        for (int o = 32; o > 0; o >>= 1) {
            contrib += __shfl_down(contrib, o);
            v += __shfl_down(v, o);
        }
        if (t == 0) {
            bsum[blockIdx.x] = contrib;
            bn[blockIdx.x] = v;
        }
    }
}

// ---------------------------------------------------------------------------
// Final: fixed-order lane-parallel sum of 256 partials (deterministic).
// ---------------------------------------------------------------------------
__global__ void final_kernel(const float* __restrict__ bsum,
                             const float* __restrict__ bn,
                             float* __restrict__ out) {
    int t = threadIdx.x; // 64 threads
    float s = 0.0f, n = 0.0f;
    for (int i = t; i < 256; i += 64) { s += bsum[i]; n += bn[i]; }
    for (int o = 32; o > 0; o >>= 1) {
        s += __shfl_down(s, o);
        n += __shfl_down(n, o);
    }
    if (t == 0) out[0] = s / n;
}

extern "C" void kernel_launch(void* const* d_in, const int* in_sizes, int n_in,
                              void* d_out, int out_size, void* d_ws, size_t ws_size,
                              hipStream_t stream) {
    const float* pred   = (const float*)d_in[0];
    const float* target = (const float*)d_in[1];
    const float* P      = (const float*)d_in[2];
    float* out = (float*)d_out;

    // choose J-slice count that fits the workspace (deterministic given ws_size)
    int JC = 128;
    while (JC > 1 && (size_t)2 * JC * NPIX * 4 + 2048 > ws_size) JC >>= 1;

    char* ws = (char*)d_ws;
    float* pm12 = (float*)ws;                 // JC*NPIX floats
    float* pm21 = pm12 + (size_t)JC * NPIX;
    float* bsum = pm21 + (size_t)JC * NPIX;   // 256 + 256
    float* bn   = bsum + 256;

    int jlen = NPIX / JC;
    dim3 grid(NPIX / ABLK, JC, 2); // (8, 128, 2) = 2048 blocks at JC=128
    pair_min_kernel<<<grid, 256, 0, stream>>>(pred, target, P, pm12, pm21, jlen);

    reduce_kernel<<<dim3(256), 256, 0, stream>>>(pm12, pm21, pred, target, P, JC, bsum, bn);
    final_kernel<<<1, 64, 0, stream>>>(bsum, bn, out);
}

// Round 11
// 52.408 us; speedup vs baseline: 1.4987x; 1.2529x over previous
//
#include <hip/hip_runtime.h>

#define NPIX 16384
#define WIDTH 128
#define RPT 8                // rows per thread
#define CPT 8                // cols per thread
#define BROWS 256            // rows per block (32 tr-groups * 8)
#define TCOLS 64             // cols per tile (8 tc-groups * 8)
#define NT 8                 // tiles per block
#define BCOLS (TCOLS * NT)   // 512 cols per block
#define RBLK (NPIX / BROWS)  // 64 row-blocks
#define CBLK (NPIX / BCOLS)  // 32 col-blocks

// order-monotone float <-> uint key (exact atomicMin on floats, any sign)
__device__ __forceinline__ unsigned fkey(float f) {
    unsigned u = __float_as_uint(f);
    return (u & 0x80000000u) ? ~u : (u | 0x80000000u);
}
__device__ __forceinline__ float funkey(unsigned k) {
    return __uint_as_float((k & 0x80000000u) ? (k ^ 0x80000000u) : ~k);
}

__device__ __forceinline__ float min3f(float a, float b, float c) {
    float d;
    asm("v_min3_f32 %0, %1, %2, %3" : "=v"(d) : "v"(a), "v"(b), "v"(c));
    return d;
}

// depth -> (x, y, z, |p|^2 + inf_add). Same math as reference pixel2xyz.
__device__ __forceinline__ float4 make_point(float d, int p,
    float fu, float cu, float p03, float fv, float cv, float p13, float p23,
    float inf_add) {
    float px = (float)(p & (WIDTH - 1));
    float py = (float)(p >> 7);
    float x = (px * (d + p23) - (cu * d + p03)) / fu;
    float y = (py * (d + p23) - (cv * d + p13)) / fv;
    float s = x * x + y * y + d * d;
    return make_float4(x, y, d, s + inf_add);
}

// ---------------------------------------------------------------------------
// ONE-PASS chamfer kernel: computes each D entry once, updating BOTH the
// row-min (dist12 partial) and col-min (dist21 partial). Thread sub-tile
// 8x8 in registers: per 2x2 micro-tile = 12 FMA + 4 add + 4 min3 = 5 VALU
// slots per unique pair (vs 7 per pair for the two-pass kernels). f includes
// wA(+inf if row invalid) and wB(+inf if col invalid), so both mins are
// fully masked and both outputs need no add-back. Cross-thread merges via
// LDS atomicMin on fkey uints (exact, order-free). No global atomics (R4),
// no broadcast-LDS inner loop (R2/R10 stall source), no pk math (R8).
// ---------------------------------------------------------------------------
__global__ __launch_bounds__(256, 4) void pair_min_kernel(
    const float* __restrict__ pred,
    const float* __restrict__ target,
    const float* __restrict__ P,
    float* __restrict__ rowpm,
    float* __restrict__ colpm) {
    float fu = P[0], cu = P[2], p03 = P[3];
    float fv = P[5], cv = P[6], p13 = P[7], p23 = P[11];

    int t = threadIdx.x;
    int tr = t >> 3, tc = t & 7;
    int rb = blockIdx.x, cb = blockIdx.y;

    __shared__ alignas(16) float sBx[TCOLS], sBy[TCOLS], sBz[TCOLS], sBw[TCOLS];
    __shared__ unsigned colK[BCOLS];
    __shared__ unsigned rowK[BROWS];

    // A-state: 8 rows (target cloud), -2 folded, w carries A-side inf.
    int rowbase = rb * BROWS + tr * RPT;
    float ax[RPT], ay[RPT], az[RPT], aw[RPT], mn[RPT];
    #pragma unroll
    for (int r = 0; r < RPT; ++r) {
        int row = rowbase + r;
        float dt = target[row];
        float inf_add = (dt > 0.0f) ? 0.0f : 1e30f;
        float4 pa = make_point(dt, row, fu, cu, p03, fv, cv, p13, p23, inf_add);
        ax[r] = -2.0f * pa.x;
        ay[r] = -2.0f * pa.y;
        az[r] = -2.0f * pa.z;
        aw[r] = pa.w;
        mn[r] = 3e38f;
    }

    colK[t] = 0xFFFFFFFFu;
    colK[t + 256] = 0xFFFFFFFFu;
    rowK[t] = 0xFFFFFFFFu;

    for (int ti = 0; ti < NT; ++ti) {
        __syncthreads();
        if (t < TCOLS) {
            int col = cb * BCOLS + ti * TCOLS + t;
            float tb = target[col];
            float inf_add = (tb > 0.0f) ? 0.0f : 1e30f;
            float4 b = make_point(pred[col], col, fu, cu, p03, fv, cv, p13, p23, inf_add);
            sBx[t] = b.x; sBy[t] = b.y; sBz[t] = b.z; sBw[t] = b.w;
        }
        __syncthreads();

        // per-thread 8 cols into registers (forced b128 LDS reads)
        int base = tc * CPT;
        float bx[CPT], by[CPT], bz[CPT], bw[CPT], cp[CPT];
        {
            float4 x0 = *(const float4*)&sBx[base], x1 = *(const float4*)&sBx[base + 4];
            float4 y0 = *(const float4*)&sBy[base], y1 = *(const float4*)&sBy[base + 4];
            float4 z0 = *(const float4*)&sBz[base], z1 = *(const float4*)&sBz[base + 4];
            float4 w0 = *(const float4*)&sBw[base], w1 = *(const float4*)&sBw[base + 4];
            bx[0]=x0.x; bx[1]=x0.y; bx[2]=x0.z; bx[3]=x0.w; bx[4]=x1.x; bx[5]=x1.y; bx[6]=x1.z; bx[7]=x1.w;
            by[0]=y0.x; by[1]=y0.y; by[2]=y0.z; by[3]=y0.w; by[4]=y1.x; by[5]=y1.y; by[6]=y1.z; by[7]=y1.w;
            bz[0]=z0.x; bz[1]=z0.y; bz[2]=z0.z; bz[3]=z0.w; bz[4]=z1.x; bz[5]=z1.y; bz[6]=z1.z; bz[7]=z1.w;
            bw[0]=w0.x; bw[1]=w0.y; bw[2]=w0.z; bw[3]=w0.w; bw[4]=w1.x; bw[5]=w1.y; bw[6]=w1.z; bw[7]=w1.w;
        }
        #pragma unroll
        for (int c = 0; c < CPT; ++c) cp[c] = 3e38f;

        #pragma unroll
        for (int c = 0; c < CPT; c += 2) {
            #pragma unroll
            for (int r = 0; r < RPT; r += 2) {
                float f00 = aw[r]     + fmaf(ax[r],     bx[c],     fmaf(ay[r],     by[c],     fmaf(az[r],     bz[c],     bw[c])));
                float f01 = aw[r]     + fmaf(ax[r],     bx[c + 1], fmaf(ay[r],     by[c + 1], fmaf(az[r],     bz[c + 1], bw[c + 1])));
                float f10 = aw[r + 1] + fmaf(ax[r + 1], bx[c],     fmaf(ay[r + 1], by[c],     fmaf(az[r + 1], bz[c],     bw[c])));
                float f11 = aw[r + 1] + fmaf(ax[r + 1], bx[c + 1], fmaf(ay[r + 1], by[c + 1], fmaf(az[r + 1], bz[c + 1], bw[c + 1])));
                mn[r]     = min3f(f00, f01, mn[r]);
                mn[r + 1] = min3f(f10, f11, mn[r + 1]);
                cp[c]     = min3f(f00, f10, cp[c]);
                cp[c + 1] = min3f(f01, f11, cp[c + 1]);
            }
        }

        int cbase = ti * TCOLS + tc * CPT;
        #pragma unroll
        for (int c = 0; c < CPT; ++c)
            atomicMin(&colK[cbase + c], fkey(cp[c]));
    }

    #pragma unroll
    for (int r = 0; r < RPT; ++r)
        atomicMin(&rowK[tr * RPT + r], fkey(mn[r]));
    __syncthreads();

    rowpm[cb * NPIX + rb * BROWS + t] = funkey(rowK[t]);
    colpm[rb * NPIX + cb * BCOLS + t]       = funkey(colK[t]);
    colpm[rb * NPIX + cb * BCOLS + 256 + t] = funkey(colK[t + 256]);
}

// ---------------------------------------------------------------------------
// Reduce: per pixel, min over 32 row-partials (dist12) and 64 col-partials
// (dist21) — no add-back needed (f carried |a|^2 and |b|^2). Masked sum in
// fixed order (deterministic).
// ---------------------------------------------------------------------------
__global__ __launch_bounds__(256) void reduce_kernel(
    const float* __restrict__ rowpm,
    const float* __restrict__ colpm,
    const float* __restrict__ target,
    float* __restrict__ bsum,
    float* __restrict__ bn) {
    int t = threadIdx.x;
    int al = t & 63, q = t >> 6;
    int a = blockIdx.x * 64 + al;

    float d12 = 3e38f, d21 = 3e38f;
    for (int cb = q * (CBLK / 4); cb < (q + 1) * (CBLK / 4); ++cb)
        d12 = fminf(d12, rowpm[cb * NPIX + a]);
    for (int rbk = q * (RBLK / 4); rbk < (q + 1) * (RBLK / 4); ++rbk)
        d21 = fminf(d21, colpm[rbk * NPIX + a]);

    __shared__ float s12[4][64], s21[4][64];
    s12[q][al] = d12;
    s21[q][al] = d21;
    __syncthreads();

    if (t < 64) {
        d12 = fminf(fminf(s12[0][t], s12[1][t]), fminf(s12[2][t], s12[3][t]));
        d21 = fminf(fminf(s21[0][t], s21[1][t]), fminf(s21[2][t], s21[3][t]));
        float v = (target[a] > 0.0f) ? 1.0f : 0.0f;
        float contrib = v * (d12 + d21);
        for (int o = 32; o > 0; o >>= 1) {
            contrib += __shfl_down(contrib, o);
            v += __shfl_down(v, o);
        }
        if (t == 0) {
            bsum[blockIdx.x] = contrib;
            bn[blockIdx.x] = v;
        }
    }
}

// ---------------------------------------------------------------------------
// Final: fixed-order lane-parallel sum of 256 partials (deterministic).
// ---------------------------------------------------------------------------
__global__ void final_kernel(const float* __restrict__ bsum,
                             const float* __restrict__ bn,
                             float* __restrict__ out) {
    int t = threadIdx.x; // 64 threads
    float s = 0.0f, n = 0.0f;
    for (int i = t; i < 256; i += 64) { s += bsum[i]; n += bn[i]; }
    for (int o = 32; o > 0; o >>= 1) {
        s += __shfl_down(s, o);
        n += __shfl_down(n, o);
    }
    if (t == 0) out[0] = s / n;
}

extern "C" void kernel_launch(void* const* d_in, const int* in_sizes, int n_in,
                              void* d_out, int out_size, void* d_ws, size_t ws_size,
                              hipStream_t stream) {
    const float* pred   = (const float*)d_in[0];
    const float* target = (const float*)d_in[1];
    const float* P      = (const float*)d_in[2];
    float* out = (float*)d_out;

    char* ws = (char*)d_ws;
    float* rowpm = (float*)ws;                              // CBLK*NPIX floats (2 MB)
    float* colpm = rowpm + (size_t)CBLK * NPIX;             // RBLK*NPIX floats (4 MB)
    float* bsum  = colpm + (size_t)RBLK * NPIX;             // 256
    float* bn    = bsum + 256;

    dim3 grid(RBLK, CBLK);   // (64, 32) = 2048 blocks
    pair_min_kernel<<<grid, 256, 0, stream>>>(pred, target, P, rowpm, colpm);

    reduce_kernel<<<dim3(NPIX / 64), 256, 0, stream>>>(rowpm, colpm, target, bsum, bn);
    final_kernel<<<1, 64, 0, stream>>>(bsum, bn, out);
}